// Round 8
// baseline (2244.182 us; speedup 1.0000x reference)
//
#include <hip/hip_runtime.h>

#define NROWS 16384
#define DIMIN 1024
#define DIMH  512
#define MEMN  8192
#define NSPLIT 8
#define CSLOTS 16
#define TAU 0.15f
#define RB 8

typedef __attribute__((ext_vector_type(8))) short bf16x8;
typedef __attribute__((ext_vector_type(8))) _Float16 f16x8;
typedef __attribute__((ext_vector_type(4))) float f32x4;

__device__ __forceinline__ unsigned short bf16_rne(float x) {
    unsigned u = __builtin_bit_cast(unsigned, x);
    unsigned r = u + 0x7fffu + ((u >> 16) & 1u);
    return (unsigned short)(r >> 16);
}
__device__ __forceinline__ float bf16_to_f(unsigned short h) {
    unsigned u = ((unsigned)h) << 16;
    return __builtin_bit_cast(float, u);
}
__device__ __forceinline__ void async_copy16(const void* g, void* l) {
    __builtin_amdgcn_global_load_lds(
        (const __attribute__((address_space(1))) unsigned int*)g,
        (__attribute__((address_space(3))) unsigned int*)l, 16, 0, 0);
}

// ---------- mm[j] = sum memory[j]^2 ; M16 = fp16(memory) for the argmin ----------
__global__ __launch_bounds__(256) void k_sumsq_split(const float* __restrict__ mem,
                                                     float* __restrict__ mm,
                                                     unsigned short* __restrict__ M16) {
    int wave = threadIdx.x >> 6, lane = threadIdx.x & 63;
    int row = blockIdx.x * 4 + wave;
    const float4* r4 = (const float4*)(mem + (size_t)row * DIMH);
    float4 a = r4[2 * lane], b = r4[2 * lane + 1];
    float x[8] = {a.x, a.y, a.z, a.w, b.x, b.y, b.z, b.w};
    union { _Float16 hf[8]; int4 v; } hv;
    float s = 0.f;
    #pragma unroll
    for (int i = 0; i < 8; ++i) {
        s = fmaf(x[i], x[i], s);
        hv.hf[i] = (_Float16)x[i];
    }
    #pragma unroll
    for (int off = 32; off; off >>= 1) s += __shfl_xor(s, off, 64);
    *(int4*)(M16 + (size_t)row * DIMH + lane * 8) = hv.v;
    if (lane == 0) mm[row] = s;
}

// ---------- generic fp32 -> bf16 hi/lo splitter (8 elems/thread) ----------
__global__ __launch_bounds__(256) void k_split(const float* __restrict__ x,
                                               unsigned short* __restrict__ h,
                                               unsigned short* __restrict__ l, int n) {
    int i = (blockIdx.x * 256 + threadIdx.x) * 8;
    if (i >= n) return;
    const float4* xp = (const float4*)(x + i);
    float4 a = xp[0], b = xp[1];
    float v[8] = {a.x, a.y, a.z, a.w, b.x, b.y, b.z, b.w};
    union { unsigned short us[8]; int4 q; } hv, lv;
    #pragma unroll
    for (int j = 0; j < 8; ++j) {
        unsigned short hh = bf16_rne(v[j]);
        hv.us[j] = hh;
        lv.us[j] = bf16_rne(v[j] - bf16_to_f(hh));
    }
    *(int4*)(h + i) = hv.q;
    *(int4*)(l + i) = lv.q;
}

// ---------- p = visual @ Wp^T + b : split-bf16 MFMA; outputs Ph/Pl (upd) + P16 (argmin) ----------
__global__ __launch_bounds__(256, 2) void k_proj_mfma(
        const float* __restrict__ A,
        const unsigned short* __restrict__ Bh, const unsigned short* __restrict__ Bl,
        const float* __restrict__ bias,
        unsigned short* __restrict__ Ph, unsigned short* __restrict__ Pl,
        unsigned short* __restrict__ P16) {
    __shared__ unsigned short sAh[128 * 32];
    __shared__ unsigned short sAl[128 * 32];
    __shared__ unsigned short sBh[128 * 32];
    __shared__ unsigned short sBl[128 * 32];
    const int t = threadIdx.x, w = t >> 6, l = t & 63;
    const int wm = w >> 1, wn = w & 1, lane16 = l & 15, quad = l >> 4;
    const int bm = blockIdx.x * 128, bn = blockIdx.y * 128;
    const int r0 = t >> 2, k0 = (t & 3) * 8, r1 = (t + 256) >> 2;
    const int lds0 = t * 8, lds1 = t * 8 + 2048;
    const int ar = t >> 1, ak = (t & 1) * 16;

    f32x4 acc[4][4];
    #pragma unroll
    for (int mf = 0; mf < 4; ++mf)
        #pragma unroll
        for (int nf = 0; nf < 4; ++nf) acc[mf][nf] = (f32x4){0.f, 0.f, 0.f, 0.f};

    for (int kc = 0; kc < DIMIN; kc += 32) {
        async_copy16(Bh + (size_t)(bn + r0) * DIMIN + kc + k0, sBh + lds0);
        async_copy16(Bh + (size_t)(bn + r1) * DIMIN + kc + k0, sBh + lds1);
        async_copy16(Bl + (size_t)(bn + r0) * DIMIN + kc + k0, sBl + lds0);
        async_copy16(Bl + (size_t)(bn + r1) * DIMIN + kc + k0, sBl + lds1);
        {
            const float4* ap = (const float4*)(A + (size_t)(bm + ar) * DIMIN + kc + ak);
            float4 v0 = ap[0], v1 = ap[1], v2 = ap[2], v3 = ap[3];
            float x[16] = {v0.x, v0.y, v0.z, v0.w, v1.x, v1.y, v1.z, v1.w,
                           v2.x, v2.y, v2.z, v2.w, v3.x, v3.y, v3.z, v3.w};
            union { unsigned short us[16]; int4 q[2]; } hv, lv;
            #pragma unroll
            for (int j = 0; j < 16; ++j) {
                unsigned short hh = bf16_rne(x[j]);
                hv.us[j] = hh;
                lv.us[j] = bf16_rne(x[j] - bf16_to_f(hh));
            }
            *(int4*)(sAh + ar * 32 + ak) = hv.q[0];
            *(int4*)(sAh + ar * 32 + ak + 8) = hv.q[1];
            *(int4*)(sAl + ar * 32 + ak) = lv.q[0];
            *(int4*)(sAl + ar * 32 + ak + 8) = lv.q[1];
        }
        __syncthreads();
        bf16x8 ah[4], al[4];
        #pragma unroll
        for (int mf = 0; mf < 4; ++mf) {
            int r = wm * 64 + mf * 16 + lane16;
            ah[mf] = *(const bf16x8*)(sAh + r * 32 + quad * 8);
            al[mf] = *(const bf16x8*)(sAl + r * 32 + quad * 8);
        }
        #pragma unroll
        for (int nf = 0; nf < 4; ++nf) {
            int r = wn * 64 + nf * 16 + lane16;
            bf16x8 bh = *(const bf16x8*)(sBh + r * 32 + quad * 8);
            bf16x8 bl = *(const bf16x8*)(sBl + r * 32 + quad * 8);
            #pragma unroll
            for (int mf = 0; mf < 4; ++mf) {
                acc[mf][nf] = __builtin_amdgcn_mfma_f32_16x16x32_bf16(ah[mf], bh, acc[mf][nf], 0, 0, 0);
                acc[mf][nf] = __builtin_amdgcn_mfma_f32_16x16x32_bf16(ah[mf], bl, acc[mf][nf], 0, 0, 0);
                acc[mf][nf] = __builtin_amdgcn_mfma_f32_16x16x32_bf16(al[mf], bh, acc[mf][nf], 0, 0, 0);
            }
        }
        __syncthreads();
    }
    #pragma unroll
    for (int nf = 0; nf < 4; ++nf) {
        int col = bn + wn * 64 + nf * 16 + lane16;
        float bb = bias[col];
        #pragma unroll
        for (int mf = 0; mf < 4; ++mf)
            #pragma unroll
            for (int r = 0; r < 4; ++r) {
                int row = bm + wm * 64 + mf * 16 + quad * 4 + r;
                float o = acc[mf][nf][r] + bb;
                unsigned short hh = bf16_rne(o);
                unsigned short ll = bf16_rne(o - bf16_to_f(hh));
                Ph[(size_t)row * DIMH + col] = hh;
                Pl[(size_t)row * DIMH + col] = ll;
                _Float16 h16 = (_Float16)o;
                P16[(size_t)row * DIMH + col] = __builtin_bit_cast(unsigned short, h16);
            }
    }
}

// ---------- fp16 single-MFMA argmin: 128x128 tile, 8 waves, 32KB dbuf LDS ----------
// -> 4 blocks/CU (launch_bounds(512,8) caps VGPR at 64). Counted vmcnt(2).
// fp16 error sigma_d2 ~0.026 pairwise; TAU=0.15 ~ 5.9 sigma + exact rescan tier-2.
__global__ __launch_bounds__(512, 8) void k_argmin_mfma(
        const unsigned short* __restrict__ P16,
        const unsigned short* __restrict__ M16,
        const float* __restrict__ mm,
        float* __restrict__ cval, int* __restrict__ cidx,
        float* __restrict__ cv2, int* __restrict__ cidx2) {
    __shared__ unsigned short lds[2 * 2 * 4096];  // 32 KB: [buf][A16 B16][128*32]
    const int t = threadIdx.x;
    const int w = t >> 6, l = t & 63;
    const int wm = w >> 1, wn = w & 1;            // 4(M) x 2(N) wave grid, wave-tile 32x64
    const int lane16 = l & 15, quad = l >> 4;
    const int split = blockIdx.x & 7;             // XCD-affine: split s -> XCD s
    const int bm = (blockIdx.x >> 3) * 128;
    const int nbase = split * (MEMN / NSPLIT);    // 1024 candidate cols per split

    const int r = t >> 2, c = t & 3;              // staging: 4 lanes cover one 64B row seg
    const int aro = (wm * 32 + lane16) * 32 + quad * 8;   // + mf*512
    const int bro = (wn * 64 + lane16) * 32 + quad * 8;   // + nf*512

#define AM_STAGE(B, CT, KC) do {                                          \
    unsigned short* Lb_ = lds + (B) * 8192;                               \
    const size_t a_ = (size_t)(bm + r) * DIMH + (KC) + c * 8;             \
    const size_t b_ = (size_t)(nbase + (CT) * 128 + r) * DIMH + (KC) + c * 8; \
    async_copy16(P16 + a_, Lb_ + t * 8);                                  \
    async_copy16(M16 + b_, Lb_ + 4096 + t * 8);                           \
} while (0)

    float bestv[8], bestv2[8];
    unsigned pk[8];                               // lo16 = best idx, hi16 = 2nd idx
    #pragma unroll
    for (int s = 0; s < 8; ++s) { bestv[s] = 3.4e38f; bestv2[s] = 3.4e38f; pk[s] = 0u; }

    f32x4 acc[2][4];
    #pragma unroll
    for (int mf = 0; mf < 2; ++mf)
        #pragma unroll
        for (int nf = 0; nf < 4; ++nf) acc[mf][nf] = (f32x4){0.f, 0.f, 0.f, 0.f};

    // 128 steps: 8 col-tiles x 16 K-tiles, buffers alternate by step parity
    AM_STAGE(0, 0, 0);
    #pragma unroll 2
    for (int s = 0; s < 128; ++s) {
        const unsigned short* Lb = lds + (s & 1) * 8192;
        if (s < 127) {
            const int sn = s + 1;
            AM_STAGE(sn & 1, sn >> 4, (sn & 15) * 32);
            asm volatile("s_waitcnt vmcnt(2)" ::: "memory");  // drain only tile s's loads
        } else {
            asm volatile("s_waitcnt vmcnt(0)" ::: "memory");
        }
        __builtin_amdgcn_s_barrier();
        f16x8 ah[2];
        ah[0] = *(const f16x8*)(Lb + aro);
        ah[1] = *(const f16x8*)(Lb + aro + 512);
        __builtin_amdgcn_s_setprio(1);
        #pragma unroll
        for (int nf = 0; nf < 4; ++nf) {
            f16x8 bh = *(const f16x8*)(Lb + 4096 + bro + nf * 512);
            #pragma unroll
            for (int mf = 0; mf < 2; ++mf) {
                acc[mf][nf] = __builtin_amdgcn_mfma_f32_16x16x32_f16(ah[mf], bh, acc[mf][nf], 0, 0, 0);
            }
        }
        __builtin_amdgcn_s_setprio(0);
        __builtin_amdgcn_s_barrier();
        if ((s & 15) == 15) {   // col-tile done: fold acc into per-slot top-2
            const int ntile = nbase + (s >> 4) * 128;
            #pragma unroll
            for (int nf = 0; nf < 4; ++nf) {
                const int n = ntile + wn * 64 + nf * 16 + lane16;
                const float mmv = mm[n];
                #pragma unroll
                for (int mf = 0; mf < 2; ++mf)
                    #pragma unroll
                    for (int rr = 0; rr < 4; ++rr) {
                        const float sv = fmaf(-2.0f, acc[mf][nf][rr], mmv);
                        const int slot = mf * 4 + rr;
                        if (sv < bestv[slot]) {
                            bestv2[slot] = bestv[slot];
                            pk[slot] = (pk[slot] << 16) | (unsigned)n;
                            bestv[slot] = sv;
                        } else if (sv < bestv2[slot]) {
                            bestv2[slot] = sv;
                            pk[slot] = (pk[slot] & 0xffffu) | ((unsigned)n << 16);
                        }
                        acc[mf][nf][rr] = 0.f;
                    }
            }
        }
    }
#undef AM_STAGE

    // top-2 merge across the 16 column lanes (ties resolved exactly by k_rescan)
    #pragma unroll
    for (int off = 1; off < 16; off <<= 1) {
        #pragma unroll
        for (int s = 0; s < 8; ++s) {
            const float ov = __shfl_xor(bestv[s], off, 64);
            const float o2 = __shfl_xor(bestv2[s], off, 64);
            const unsigned opk = (unsigned)__shfl_xor((int)pk[s], off, 64);
            const float bv = bestv[s], b2 = bestv2[s];
            const unsigned p = pk[s];
            if (bv <= ov) {
                if (ov < b2) { bestv2[s] = ov; pk[s] = (p & 0xffffu) | (opk << 16); }
            } else {
                bestv[s] = ov;
                if (bv < o2) { bestv2[s] = bv; pk[s] = (opk & 0xffffu) | (p << 16); }
                else         { bestv2[s] = o2; pk[s] = opk; }
            }
        }
    }
    if (lane16 == 0) {
        const int slot = split * 2 + wn;
        #pragma unroll
        for (int mf = 0; mf < 2; ++mf)
            #pragma unroll
            for (int rr = 0; rr < 4; ++rr) {
                const int row = bm + wm * 32 + mf * 16 + quad * 4 + rr;
                const int si = mf * 4 + rr;
                const size_t o = (size_t)row * CSLOTS + slot;
                cval[o] = bestv[si];
                cidx[o] = (int)(pk[si] & 0xffffu);
                cv2[o]  = bestv2[si];
                cidx2[o] = (int)(pk[si] >> 16);
            }
    }
}

// ---------- merge slots -> global best; flag rows with gap < TAU; gather ----------
__global__ __launch_bounds__(256) void k_merge_gather(const float* __restrict__ cval,
                                                      const int* __restrict__ cidx,
                                                      const float* __restrict__ cv2,
                                                      const float* __restrict__ Mem,
                                                      float* __restrict__ out0,
                                                      int* __restrict__ bidx,
                                                      int* __restrict__ count,
                                                      int* __restrict__ list) {
    int wave = threadIdx.x >> 6, lane = threadIdx.x & 63;
    int row = blockIdx.x * 4 + wave;
    float v1 = 3.4e38f, v2 = 3.4e38f;
    int i1 = 0;
    #pragma unroll
    for (int s = 0; s < CSLOTS; ++s) {
        float a1 = cval[(size_t)row * CSLOTS + s];
        float b2 = cv2[(size_t)row * CSLOTS + s];
        int   ai = cidx[(size_t)row * CSLOTS + s];
        if (a1 < v1 || (a1 == v1 && ai < i1)) {
            v2 = fminf(v1, b2);
            v1 = a1; i1 = ai;
        } else {
            v2 = fminf(v2, a1);
        }
    }
    if (lane == 0) {
        bidx[row] = i1;
        if (v2 - v1 < TAU) {
            int pos = atomicAdd(count, 1);
            list[pos] = row;
        }
    }
    const float4* src = (const float4*)(Mem + (size_t)i1 * DIMH);
    float4* dst = (float4*)(out0 + (size_t)row * DIMH);
    dst[lane] = src[lane];
    dst[lane + 64] = src[lane + 64];
}

// ---------- exact fp32 re-decision, ROW-BATCHED: 8 rows share one Wp sweep ----------
__global__ __launch_bounds__(256) void k_rescan(const float* __restrict__ visual,
                                                const float* __restrict__ Wp,
                                                const float* __restrict__ bp,
                                                const float* __restrict__ Mem,
                                                const float* __restrict__ mm,
                                                const int* __restrict__ count,
                                                const int* __restrict__ list,
                                                const int* __restrict__ cidx,
                                                const int* __restrict__ cidx2,
                                                int* __restrict__ bidx,
                                                float* __restrict__ out0) {
    __shared__ float vrow[RB][DIMIN];   // 32 KB
    __shared__ float p[RB][DIMH];       // 16 KB
    __shared__ float sv[32];
    __shared__ int   si[32];
    __shared__ int   sbest;
    const int t = threadIdx.x;
    int cnt = *count;
    if (cnt > NROWS) cnt = NROWS;
    for (int base = blockIdx.x * RB; base < cnt; base += gridDim.x * RB) {
        const int nb = (cnt - base < RB) ? (cnt - base) : RB;
        __syncthreads();   // protect vrow/p reuse across grid-stride iterations
        for (int j = 0; j < nb; ++j) {
            int row = list[base + j];
            *(float4*)&vrow[j][t * 4] = *(const float4*)(visual + (size_t)row * DIMIN + t * 4);
        }
        __syncthreads();
        // exact fp32 projection for the batch: thread t handles cols t and t+256
        {
            float acc0[RB], acc1[RB];
            #pragma unroll
            for (int j = 0; j < RB; ++j) { acc0[j] = 0.f; acc1[j] = 0.f; }
            const float* w0p = Wp + (size_t)t * DIMIN;
            const float* w1p = Wp + (size_t)(t + 256) * DIMIN;
            for (int k = 0; k < DIMIN; k += 4) {
                float4 w0 = *(const float4*)(w0p + k);
                float4 w1 = *(const float4*)(w1p + k);
                #pragma unroll
                for (int j = 0; j < RB; ++j) {
                    float4 x = *(const float4*)&vrow[j][k];   // LDS broadcast
                    acc0[j] = fmaf(w0.x, x.x, fmaf(w0.y, x.y, fmaf(w0.z, x.z, fmaf(w0.w, x.w, acc0[j]))));
                    acc1[j] = fmaf(w1.x, x.x, fmaf(w1.y, x.y, fmaf(w1.z, x.z, fmaf(w1.w, x.w, acc1[j]))));
                }
            }
            float b0 = bp[t], b1 = bp[t + 256];
            #pragma unroll
            for (int j = 0; j < RB; ++j) {
                p[j][t] = b0 + acc0[j];
                p[j][t + 256] = b1 + acc1[j];
            }
        }
        __syncthreads();
        // per-row decision among the 32 stored candidates (unchanged semantics)
        for (int j = 0; j < nb; ++j) {
            int row = list[base + j];
            int g = t >> 3, sub = t & 7;
            int cand = (g < 16) ? cidx[(size_t)row * CSLOTS + g]
                                : cidx2[(size_t)row * CSLOTS + (g - 16)];
            const float* mr = Mem + (size_t)cand * DIMH + sub * 64;
            const float* pj = p[j] + sub * 64;
            float d = 0.f;
            for (int k = 0; k < 64; k += 4) {
                float4 mv = *(const float4*)(mr + k);
                float4 pv = *(const float4*)(pj + k);
                d = fmaf(mv.x, pv.x, fmaf(mv.y, pv.y, fmaf(mv.z, pv.z, fmaf(mv.w, pv.w, d))));
            }
            #pragma unroll
            for (int off = 1; off < 8; off <<= 1) d += __shfl_xor(d, off, 64);
            if (sub == 0) {
                sv[g] = fmaf(-2.f, d, mm[cand]);
                si[g] = cand;
            }
            __syncthreads();
            if (t == 0) {
                float bv = sv[0]; int bi = si[0];
                for (int gg = 1; gg < 32; ++gg) {
                    float v = sv[gg]; int ii = si[gg];
                    if (v < bv || (v == bv && ii < bi)) { bv = v; bi = ii; }
                }
                bidx[row] = bi;
                sbest = bi;
            }
            __syncthreads();
            int best = sbest;
            if (t < 128)
                *(float4*)(out0 + (size_t)row * DIMH + t * 4) =
                    *(const float4*)(Mem + (size_t)best * DIMH + t * 4);
        }
    }
}

// ---------- upd = ((Ph+Pl) - mem[bidx]) @ Wu^T + b; out1[bidx] += 0.5*upd ----------
__global__ __launch_bounds__(256, 2) void k_upd_mfma(
        const unsigned short* __restrict__ Ph, const unsigned short* __restrict__ Pl,
        const float* __restrict__ Mem, const int* __restrict__ bidx,
        const unsigned short* __restrict__ Bh, const unsigned short* __restrict__ Bl,
        const float* __restrict__ bias, float* __restrict__ out1) {
    __shared__ unsigned short sAh[128 * 32];
    __shared__ unsigned short sAl[128 * 32];
    __shared__ unsigned short sBh[128 * 32];
    __shared__ unsigned short sBl[128 * 32];
    __shared__ int ridx[128];
    const int t = threadIdx.x, w = t >> 6, l = t & 63;
    const int wm = w >> 1, wn = w & 1, lane16 = l & 15, quad = l >> 4;
    const int bm = blockIdx.x * 128, bn = blockIdx.y * 128;
    const int r0 = t >> 2, k0 = (t & 3) * 8, r1 = (t + 256) >> 2;
    const int lds0 = t * 8, lds1 = t * 8 + 2048;
    const int ar = t >> 1, ak = (t & 1) * 16;
    if (t < 128) ridx[t] = bidx[bm + t];
    __syncthreads();

    f32x4 acc[4][4];
    #pragma unroll
    for (int mf = 0; mf < 4; ++mf)
        #pragma unroll
        for (int nf = 0; nf < 4; ++nf) acc[mf][nf] = (f32x4){0.f, 0.f, 0.f, 0.f};

    for (int kc = 0; kc < DIMH; kc += 32) {
        async_copy16(Bh + (size_t)(bn + r0) * DIMH + kc + k0, sBh + lds0);
        async_copy16(Bh + (size_t)(bn + r1) * DIMH + kc + k0, sBh + lds1);
        async_copy16(Bl + (size_t)(bn + r0) * DIMH + kc + k0, sBl + lds0);
        async_copy16(Bl + (size_t)(bn + r1) * DIMH + kc + k0, sBl + lds1);
        {
            const unsigned short* ph = Ph + (size_t)(bm + ar) * DIMH + kc + ak;
            const unsigned short* pl = Pl + (size_t)(bm + ar) * DIMH + kc + ak;
            union { unsigned short us[16]; int4 q[2]; } hq, lq;
            hq.q[0] = *(const int4*)ph; hq.q[1] = *(const int4*)(ph + 8);
            lq.q[0] = *(const int4*)pl; lq.q[1] = *(const int4*)(pl + 8);
            const float* mrow = Mem + (size_t)ridx[ar] * DIMH + kc + ak;
            float4 m0 = *(const float4*)(mrow), m1 = *(const float4*)(mrow + 4);
            float4 m2 = *(const float4*)(mrow + 8), m3 = *(const float4*)(mrow + 12);
            float mv[16] = {m0.x, m0.y, m0.z, m0.w, m1.x, m1.y, m1.z, m1.w,
                            m2.x, m2.y, m2.z, m2.w, m3.x, m3.y, m3.z, m3.w};
            union { unsigned short us[16]; int4 q[2]; } hv, lv;
            #pragma unroll
            for (int j = 0; j < 16; ++j) {
                float d = bf16_to_f(hq.us[j]) + bf16_to_f(lq.us[j]) - mv[j];
                unsigned short hh = bf16_rne(d);
                hv.us[j] = hh;
                lv.us[j] = bf16_rne(d - bf16_to_f(hh));
            }
            *(int4*)(sAh + ar * 32 + ak) = hv.q[0];
            *(int4*)(sAh + ar * 32 + ak + 8) = hv.q[1];
            *(int4*)(sAl + ar * 32 + ak) = lv.q[0];
            *(int4*)(sAl + ar * 32 + ak + 8) = lv.q[1];
        }
        __syncthreads();
        bf16x8 ah[4], al[4];
        #pragma unroll
        for (int mf = 0; mf < 4; ++mf) {
            int r = wm * 64 + mf * 16 + lane16;
            ah[mf] = *(const bf16x8*)(sAh + r * 32 + quad * 8);
            al[mf] = *(const bf16x8*)(sAl + r * 32 + quad * 8);
        }
        #pragma unroll
        for (int nf = 0; nf < 4; ++nf) {
            int r = wn * 64 + nf * 16 + lane16;
            bf16x8 bh = *(const bf16x8*)(sBh + r * 32 + quad * 8);
            bf16x8 bl = *(const bf16x8*)(sBl + r * 32 + quad * 8);
            #pragma unroll
            for (int mf = 0; mf < 4; ++mf) {
                acc[mf][nf] = __builtin_amdgcn_mfma_f32_16x16x32_bf16(ah[mf], bh, acc[mf][nf], 0, 0, 0);
                acc[mf][nf] = __builtin_amdgcn_mfma_f32_16x16x32_bf16(ah[mf], bl, acc[mf][nf], 0, 0, 0);
                acc[mf][nf] = __builtin_amdgcn_mfma_f32_16x16x32_bf16(al[mf], bh, acc[mf][nf], 0, 0, 0);
            }
        }
        __syncthreads();
    }
    #pragma unroll
    for (int nf = 0; nf < 4; ++nf) {
        int col = bn + wn * 64 + nf * 16 + lane16;
        float bb = bias[col];
        #pragma unroll
        for (int mf = 0; mf < 4; ++mf)
            #pragma unroll
            for (int rr = 0; rr < 4; ++rr) {
                int rowl = wm * 64 + mf * 16 + quad * 4 + rr;
                int tgt = ridx[rowl];
                atomicAdd(out1 + (size_t)tgt * DIMH + col, 0.5f * (acc[mf][nf][rr] + bb));
            }
    }
}

extern "C" void kernel_launch(void* const* d_in, const int* in_sizes, int n_in,
                              void* d_out, int out_size, void* d_ws, size_t ws_size,
                              hipStream_t stream) {
    const float* visual = (const float*)d_in[0];
    const float* memory = (const float*)d_in[1];
    const float* W_proj = (const float*)d_in[2];
    const float* b_proj = (const float*)d_in[3];
    const float* W_upd  = (const float*)d_in[4];
    const float* b_upd  = (const float*)d_in[5];
    float* out0 = (float*)d_out;
    float* out1 = out0 + (size_t)NROWS * DIMH;

    char* ws = (char*)d_ws;
    unsigned short* Ph  = (unsigned short*)ws;
    unsigned short* Pl  = Ph + (size_t)NROWS * DIMH;
    unsigned short* P16 = Pl + (size_t)NROWS * DIMH;
    unsigned short* M16 = P16 + (size_t)NROWS * DIMH;
    unsigned short* Wph = M16 + (size_t)MEMN * DIMH;
    unsigned short* Wpl = Wph + (size_t)DIMH * DIMIN;
    unsigned short* Wuh = Wpl + (size_t)DIMH * DIMIN;
    unsigned short* Wul = Wuh + (size_t)DIMH * DIMH;
    float* mm   = (float*)(Wul + (size_t)DIMH * DIMH);
    float* cval = mm + MEMN;
    float* cv2  = cval + (size_t)NROWS * CSLOTS;
    int*   cidx = (int*)(cv2 + (size_t)NROWS * CSLOTS);
    int*   cidx2 = cidx + (size_t)NROWS * CSLOTS;
    int*   bidx = cidx2 + (size_t)NROWS * CSLOTS;
    int*   list = bidx + NROWS;
    int*   count = list + NROWS;

    k_sumsq_split<<<MEMN / 4, 256, 0, stream>>>(memory, mm, M16);
    k_split<<<(DIMH * DIMIN) / (8 * 256), 256, 0, stream>>>(W_proj, Wph, Wpl, DIMH * DIMIN);
    k_split<<<(DIMH * DIMH) / (8 * 256), 256, 0, stream>>>(W_upd, Wuh, Wul, DIMH * DIMH);
    k_proj_mfma<<<dim3(NROWS / 128, DIMH / 128), 256, 0, stream>>>(
        visual, Wph, Wpl, b_proj, Ph, Pl, P16);
    k_argmin_mfma<<<(NROWS / 128) * NSPLIT, 512, 0, stream>>>(
        P16, M16, mm, cval, cidx, cv2, cidx2);
    hipMemsetAsync(count, 0, 4, stream);
    k_merge_gather<<<NROWS / 4, 256, 0, stream>>>(
        cval, cidx, cv2, memory, out0, bidx, count, list);
    k_rescan<<<1024, 256, 0, stream>>>(
        visual, W_proj, b_proj, memory, mm, count, list, cidx, cidx2, bidx, out0);
    hipMemcpyAsync(out1, memory, (size_t)MEMN * DIMH * 4, hipMemcpyDeviceToDevice, stream);
    k_upd_mfma<<<dim3(NROWS / 128, DIMH / 128), 256, 0, stream>>>(
        Ph, Pl, memory, bidx, Wuh, Wul, b_upd, out1);
}

// Round 9
// 593.228 us; speedup vs baseline: 3.7830x; 3.7830x over previous
//
#include <hip/hip_runtime.h>

#define NROWS 16384
#define DIMIN 1024
#define DIMH  512
#define MEMN  8192
#define NSPLIT 8
#define CSLOTS 16
#define TAU 0.15f
#define RB 8

typedef __attribute__((ext_vector_type(8))) short bf16x8;
typedef __attribute__((ext_vector_type(8))) _Float16 f16x8;
typedef __attribute__((ext_vector_type(4))) float f32x4;

__device__ __forceinline__ unsigned short bf16_rne(float x) {
    unsigned u = __builtin_bit_cast(unsigned, x);
    unsigned r = u + 0x7fffu + ((u >> 16) & 1u);
    return (unsigned short)(r >> 16);
}
__device__ __forceinline__ float bf16_to_f(unsigned short h) {
    unsigned u = ((unsigned)h) << 16;
    return __builtin_bit_cast(float, u);
}
__device__ __forceinline__ void async_copy16(const void* g, void* l) {
    __builtin_amdgcn_global_load_lds(
        (const __attribute__((address_space(1))) unsigned int*)g,
        (__attribute__((address_space(3))) unsigned int*)l, 16, 0, 0);
}

// ---------- mm[j] = sum memory[j]^2 ; M16 = fp16(memory) for the argmin ----------
__global__ __launch_bounds__(256) void k_sumsq_split(const float* __restrict__ mem,
                                                     float* __restrict__ mm,
                                                     unsigned short* __restrict__ M16) {
    int wave = threadIdx.x >> 6, lane = threadIdx.x & 63;
    int row = blockIdx.x * 4 + wave;
    const float4* r4 = (const float4*)(mem + (size_t)row * DIMH);
    float4 a = r4[2 * lane], b = r4[2 * lane + 1];
    float x[8] = {a.x, a.y, a.z, a.w, b.x, b.y, b.z, b.w};
    union { _Float16 hf[8]; int4 v; } hv;
    float s = 0.f;
    #pragma unroll
    for (int i = 0; i < 8; ++i) {
        s = fmaf(x[i], x[i], s);
        hv.hf[i] = (_Float16)x[i];
    }
    #pragma unroll
    for (int off = 32; off; off >>= 1) s += __shfl_xor(s, off, 64);
    *(int4*)(M16 + (size_t)row * DIMH + lane * 8) = hv.v;
    if (lane == 0) mm[row] = s;
}

// ---------- generic fp32 -> bf16 hi/lo splitter (8 elems/thread) ----------
__global__ __launch_bounds__(256) void k_split(const float* __restrict__ x,
                                               unsigned short* __restrict__ h,
                                               unsigned short* __restrict__ l, int n) {
    int i = (blockIdx.x * 256 + threadIdx.x) * 8;
    if (i >= n) return;
    const float4* xp = (const float4*)(x + i);
    float4 a = xp[0], b = xp[1];
    float v[8] = {a.x, a.y, a.z, a.w, b.x, b.y, b.z, b.w};
    union { unsigned short us[8]; int4 q; } hv, lv;
    #pragma unroll
    for (int j = 0; j < 8; ++j) {
        unsigned short hh = bf16_rne(v[j]);
        hv.us[j] = hh;
        lv.us[j] = bf16_rne(v[j] - bf16_to_f(hh));
    }
    *(int4*)(h + i) = hv.q;
    *(int4*)(l + i) = lv.q;
}

// ---------- p = visual @ Wp^T + b : split-bf16 MFMA; outputs Ph/Pl (upd) + P16 (argmin) ----------
__global__ __launch_bounds__(256, 2) void k_proj_mfma(
        const float* __restrict__ A,
        const unsigned short* __restrict__ Bh, const unsigned short* __restrict__ Bl,
        const float* __restrict__ bias,
        unsigned short* __restrict__ Ph, unsigned short* __restrict__ Pl,
        unsigned short* __restrict__ P16) {
    __shared__ unsigned short sAh[128 * 32];
    __shared__ unsigned short sAl[128 * 32];
    __shared__ unsigned short sBh[128 * 32];
    __shared__ unsigned short sBl[128 * 32];
    const int t = threadIdx.x, w = t >> 6, l = t & 63;
    const int wm = w >> 1, wn = w & 1, lane16 = l & 15, quad = l >> 4;
    const int bm = blockIdx.x * 128, bn = blockIdx.y * 128;
    const int r0 = t >> 2, k0 = (t & 3) * 8, r1 = (t + 256) >> 2;
    const int lds0 = t * 8, lds1 = t * 8 + 2048;
    const int ar = t >> 1, ak = (t & 1) * 16;

    f32x4 acc[4][4];
    #pragma unroll
    for (int mf = 0; mf < 4; ++mf)
        #pragma unroll
        for (int nf = 0; nf < 4; ++nf) acc[mf][nf] = (f32x4){0.f, 0.f, 0.f, 0.f};

    for (int kc = 0; kc < DIMIN; kc += 32) {
        async_copy16(Bh + (size_t)(bn + r0) * DIMIN + kc + k0, sBh + lds0);
        async_copy16(Bh + (size_t)(bn + r1) * DIMIN + kc + k0, sBh + lds1);
        async_copy16(Bl + (size_t)(bn + r0) * DIMIN + kc + k0, sBl + lds0);
        async_copy16(Bl + (size_t)(bn + r1) * DIMIN + kc + k0, sBl + lds1);
        {
            const float4* ap = (const float4*)(A + (size_t)(bm + ar) * DIMIN + kc + ak);
            float4 v0 = ap[0], v1 = ap[1], v2 = ap[2], v3 = ap[3];
            float x[16] = {v0.x, v0.y, v0.z, v0.w, v1.x, v1.y, v1.z, v1.w,
                           v2.x, v2.y, v2.z, v2.w, v3.x, v3.y, v3.z, v3.w};
            union { unsigned short us[16]; int4 q[2]; } hv, lv;
            #pragma unroll
            for (int j = 0; j < 16; ++j) {
                unsigned short hh = bf16_rne(x[j]);
                hv.us[j] = hh;
                lv.us[j] = bf16_rne(x[j] - bf16_to_f(hh));
            }
            *(int4*)(sAh + ar * 32 + ak) = hv.q[0];
            *(int4*)(sAh + ar * 32 + ak + 8) = hv.q[1];
            *(int4*)(sAl + ar * 32 + ak) = lv.q[0];
            *(int4*)(sAl + ar * 32 + ak + 8) = lv.q[1];
        }
        __syncthreads();
        bf16x8 ah[4], al[4];
        #pragma unroll
        for (int mf = 0; mf < 4; ++mf) {
            int r = wm * 64 + mf * 16 + lane16;
            ah[mf] = *(const bf16x8*)(sAh + r * 32 + quad * 8);
            al[mf] = *(const bf16x8*)(sAl + r * 32 + quad * 8);
        }
        #pragma unroll
        for (int nf = 0; nf < 4; ++nf) {
            int r = wn * 64 + nf * 16 + lane16;
            bf16x8 bh = *(const bf16x8*)(sBh + r * 32 + quad * 8);
            bf16x8 bl = *(const bf16x8*)(sBl + r * 32 + quad * 8);
            #pragma unroll
            for (int mf = 0; mf < 4; ++mf) {
                acc[mf][nf] = __builtin_amdgcn_mfma_f32_16x16x32_bf16(ah[mf], bh, acc[mf][nf], 0, 0, 0);
                acc[mf][nf] = __builtin_amdgcn_mfma_f32_16x16x32_bf16(ah[mf], bl, acc[mf][nf], 0, 0, 0);
                acc[mf][nf] = __builtin_amdgcn_mfma_f32_16x16x32_bf16(al[mf], bh, acc[mf][nf], 0, 0, 0);
            }
        }
        __syncthreads();
    }
    #pragma unroll
    for (int nf = 0; nf < 4; ++nf) {
        int col = bn + wn * 64 + nf * 16 + lane16;
        float bb = bias[col];
        #pragma unroll
        for (int mf = 0; mf < 4; ++mf)
            #pragma unroll
            for (int r = 0; r < 4; ++r) {
                int row = bm + wm * 64 + mf * 16 + quad * 4 + r;
                float o = acc[mf][nf][r] + bb;
                unsigned short hh = bf16_rne(o);
                unsigned short ll = bf16_rne(o - bf16_to_f(hh));
                Ph[(size_t)row * DIMH + col] = hh;
                Pl[(size_t)row * DIMH + col] = ll;
                _Float16 h16 = (_Float16)o;
                P16[(size_t)row * DIMH + col] = __builtin_bit_cast(unsigned short, h16);
            }
    }
}

// ---------- fp16 single-MFMA argmin: 128x128 tile, 8 waves, 32KB dbuf LDS ----------
// launch_bounds(512,4): VGPR cap 128, compiler settles ~48-56 <= 64 so HW can still
// run 8 waves/EU; occupancy LDS-limited at 4 blocks/CU. (512,8) strangled the
// allocator to 32 VGPRs -> 4.4GB scratch (round 8). Counted vmcnt(2).
// fp16 error sigma_d2 ~0.026 pairwise; TAU=0.15 ~ 5.9 sigma + exact rescan tier-2.
__global__ __launch_bounds__(512, 4) void k_argmin_mfma(
        const unsigned short* __restrict__ P16,
        const unsigned short* __restrict__ M16,
        const float* __restrict__ mm,
        float* __restrict__ cval, int* __restrict__ cidx,
        float* __restrict__ cv2, int* __restrict__ cidx2) {
    __shared__ unsigned short lds[2 * 2 * 4096];  // 32 KB: [buf][A16 B16][128*32]
    const int t = threadIdx.x;
    const int w = t >> 6, l = t & 63;
    const int wm = w >> 1, wn = w & 1;            // 4(M) x 2(N) wave grid, wave-tile 32x64
    const int lane16 = l & 15, quad = l >> 4;
    const int split = blockIdx.x & 7;             // XCD-affine: split s -> XCD s
    const int bm = (blockIdx.x >> 3) * 128;
    const int nbase = split * (MEMN / NSPLIT);    // 1024 candidate cols per split

    const int r = t >> 2, c = t & 3;              // staging: 4 lanes cover one 64B row seg
    const int aro = (wm * 32 + lane16) * 32 + quad * 8;   // + mf*512
    const int bro = (wn * 64 + lane16) * 32 + quad * 8;   // + nf*512

#define AM_STAGE(B, CT, KC) do {                                          \
    unsigned short* Lb_ = lds + (B) * 8192;                               \
    const size_t a_ = (size_t)(bm + r) * DIMH + (KC) + c * 8;             \
    const size_t b_ = (size_t)(nbase + (CT) * 128 + r) * DIMH + (KC) + c * 8; \
    async_copy16(P16 + a_, Lb_ + t * 8);                                  \
    async_copy16(M16 + b_, Lb_ + 4096 + t * 8);                           \
} while (0)

    float bestv[8], bestv2[8];
    unsigned pk[8];                               // lo16 = best idx, hi16 = 2nd idx
    #pragma unroll
    for (int s = 0; s < 8; ++s) { bestv[s] = 3.4e38f; bestv2[s] = 3.4e38f; pk[s] = 0u; }

    f32x4 acc[2][4];
    #pragma unroll
    for (int mf = 0; mf < 2; ++mf)
        #pragma unroll
        for (int nf = 0; nf < 4; ++nf) acc[mf][nf] = (f32x4){0.f, 0.f, 0.f, 0.f};

    // 128 steps: 8 col-tiles x 16 K-tiles, buffers alternate by step parity
    AM_STAGE(0, 0, 0);
    #pragma unroll 2
    for (int s = 0; s < 128; ++s) {
        const unsigned short* Lb = lds + (s & 1) * 8192;
        if (s < 127) {
            const int sn = s + 1;
            AM_STAGE(sn & 1, sn >> 4, (sn & 15) * 32);
            asm volatile("s_waitcnt vmcnt(2)" ::: "memory");  // drain only tile s's loads
        } else {
            asm volatile("s_waitcnt vmcnt(0)" ::: "memory");
        }
        __builtin_amdgcn_s_barrier();
        f16x8 ah[2];
        ah[0] = *(const f16x8*)(Lb + aro);
        ah[1] = *(const f16x8*)(Lb + aro + 512);
        __builtin_amdgcn_s_setprio(1);
        #pragma unroll
        for (int nf = 0; nf < 4; ++nf) {
            f16x8 bh = *(const f16x8*)(Lb + 4096 + bro + nf * 512);
            #pragma unroll
            for (int mf = 0; mf < 2; ++mf) {
                acc[mf][nf] = __builtin_amdgcn_mfma_f32_16x16x32_f16(ah[mf], bh, acc[mf][nf], 0, 0, 0);
            }
        }
        __builtin_amdgcn_s_setprio(0);
        __builtin_amdgcn_s_barrier();
        if ((s & 15) == 15) {   // col-tile done: fold acc into per-slot top-2
            const int ntile = nbase + (s >> 4) * 128;
            #pragma unroll
            for (int nf = 0; nf < 4; ++nf) {
                const int n = ntile + wn * 64 + nf * 16 + lane16;
                const float mmv = mm[n];
                #pragma unroll
                for (int mf = 0; mf < 2; ++mf)
                    #pragma unroll
                    for (int rr = 0; rr < 4; ++rr) {
                        const float sv = fmaf(-2.0f, acc[mf][nf][rr], mmv);
                        const int slot = mf * 4 + rr;
                        if (sv < bestv[slot]) {
                            bestv2[slot] = bestv[slot];
                            pk[slot] = (pk[slot] << 16) | (unsigned)n;
                            bestv[slot] = sv;
                        } else if (sv < bestv2[slot]) {
                            bestv2[slot] = sv;
                            pk[slot] = (pk[slot] & 0xffffu) | ((unsigned)n << 16);
                        }
                        acc[mf][nf][rr] = 0.f;
                    }
            }
        }
    }
#undef AM_STAGE

    // top-2 merge across the 16 column lanes (ties resolved exactly by k_rescan)
    #pragma unroll
    for (int off = 1; off < 16; off <<= 1) {
        #pragma unroll
        for (int s = 0; s < 8; ++s) {
            const float ov = __shfl_xor(bestv[s], off, 64);
            const float o2 = __shfl_xor(bestv2[s], off, 64);
            const unsigned opk = (unsigned)__shfl_xor((int)pk[s], off, 64);
            const float bv = bestv[s], b2 = bestv2[s];
            const unsigned p = pk[s];
            if (bv <= ov) {
                if (ov < b2) { bestv2[s] = ov; pk[s] = (p & 0xffffu) | (opk << 16); }
            } else {
                bestv[s] = ov;
                if (bv < o2) { bestv2[s] = bv; pk[s] = (opk & 0xffffu) | (p << 16); }
                else         { bestv2[s] = o2; pk[s] = opk; }
            }
        }
    }
    if (lane16 == 0) {
        const int slot = split * 2 + wn;
        #pragma unroll
        for (int mf = 0; mf < 2; ++mf)
            #pragma unroll
            for (int rr = 0; rr < 4; ++rr) {
                const int row = bm + wm * 32 + mf * 16 + quad * 4 + rr;
                const int si = mf * 4 + rr;
                const size_t o = (size_t)row * CSLOTS + slot;
                cval[o] = bestv[si];
                cidx[o] = (int)(pk[si] & 0xffffu);
                cv2[o]  = bestv2[si];
                cidx2[o] = (int)(pk[si] >> 16);
            }
    }
}

// ---------- merge slots -> global best; flag rows with gap < TAU; gather ----------
__global__ __launch_bounds__(256) void k_merge_gather(const float* __restrict__ cval,
                                                      const int* __restrict__ cidx,
                                                      const float* __restrict__ cv2,
                                                      const float* __restrict__ Mem,
                                                      float* __restrict__ out0,
                                                      int* __restrict__ bidx,
                                                      int* __restrict__ count,
                                                      int* __restrict__ list) {
    int wave = threadIdx.x >> 6, lane = threadIdx.x & 63;
    int row = blockIdx.x * 4 + wave;
    float v1 = 3.4e38f, v2 = 3.4e38f;
    int i1 = 0;
    #pragma unroll
    for (int s = 0; s < CSLOTS; ++s) {
        float a1 = cval[(size_t)row * CSLOTS + s];
        float b2 = cv2[(size_t)row * CSLOTS + s];
        int   ai = cidx[(size_t)row * CSLOTS + s];
        if (a1 < v1 || (a1 == v1 && ai < i1)) {
            v2 = fminf(v1, b2);
            v1 = a1; i1 = ai;
        } else {
            v2 = fminf(v2, a1);
        }
    }
    if (lane == 0) {
        bidx[row] = i1;
        if (v2 - v1 < TAU) {
            int pos = atomicAdd(count, 1);
            list[pos] = row;
        }
    }
    const float4* src = (const float4*)(Mem + (size_t)i1 * DIMH);
    float4* dst = (float4*)(out0 + (size_t)row * DIMH);
    dst[lane] = src[lane];
    dst[lane + 64] = src[lane + 64];
}

// ---------- exact fp32 re-decision, ROW-BATCHED: 8 rows share one Wp sweep ----------
__global__ __launch_bounds__(256) void k_rescan(const float* __restrict__ visual,
                                                const float* __restrict__ Wp,
                                                const float* __restrict__ bp,
                                                const float* __restrict__ Mem,
                                                const float* __restrict__ mm,
                                                const int* __restrict__ count,
                                                const int* __restrict__ list,
                                                const int* __restrict__ cidx,
                                                const int* __restrict__ cidx2,
                                                int* __restrict__ bidx,
                                                float* __restrict__ out0) {
    __shared__ float vrow[RB][DIMIN];   // 32 KB
    __shared__ float p[RB][DIMH];       // 16 KB
    __shared__ float sv[32];
    __shared__ int   si[32];
    __shared__ int   sbest;
    const int t = threadIdx.x;
    int cnt = *count;
    if (cnt > NROWS) cnt = NROWS;
    for (int base = blockIdx.x * RB; base < cnt; base += gridDim.x * RB) {
        const int nb = (cnt - base < RB) ? (cnt - base) : RB;
        __syncthreads();   // protect vrow/p reuse across grid-stride iterations
        for (int j = 0; j < nb; ++j) {
            int row = list[base + j];
            *(float4*)&vrow[j][t * 4] = *(const float4*)(visual + (size_t)row * DIMIN + t * 4);
        }
        __syncthreads();
        // exact fp32 projection for the batch: thread t handles cols t and t+256
        {
            float acc0[RB], acc1[RB];
            #pragma unroll
            for (int j = 0; j < RB; ++j) { acc0[j] = 0.f; acc1[j] = 0.f; }
            const float* w0p = Wp + (size_t)t * DIMIN;
            const float* w1p = Wp + (size_t)(t + 256) * DIMIN;
            for (int k = 0; k < DIMIN; k += 4) {
                float4 w0 = *(const float4*)(w0p + k);
                float4 w1 = *(const float4*)(w1p + k);
                #pragma unroll
                for (int j = 0; j < RB; ++j) {
                    float4 x = *(const float4*)&vrow[j][k];   // LDS broadcast
                    acc0[j] = fmaf(w0.x, x.x, fmaf(w0.y, x.y, fmaf(w0.z, x.z, fmaf(w0.w, x.w, acc0[j]))));
                    acc1[j] = fmaf(w1.x, x.x, fmaf(w1.y, x.y, fmaf(w1.z, x.z, fmaf(w1.w, x.w, acc1[j]))));
                }
            }
            float b0 = bp[t], b1 = bp[t + 256];
            #pragma unroll
            for (int j = 0; j < RB; ++j) {
                p[j][t] = b0 + acc0[j];
                p[j][t + 256] = b1 + acc1[j];
            }
        }
        __syncthreads();
        // per-row decision among the 32 stored candidates (unchanged semantics)
        for (int j = 0; j < nb; ++j) {
            int row = list[base + j];
            int g = t >> 3, sub = t & 7;
            int cand = (g < 16) ? cidx[(size_t)row * CSLOTS + g]
                                : cidx2[(size_t)row * CSLOTS + (g - 16)];
            const float* mr = Mem + (size_t)cand * DIMH + sub * 64;
            const float* pj = p[j] + sub * 64;
            float d = 0.f;
            for (int k = 0; k < 64; k += 4) {
                float4 mv = *(const float4*)(mr + k);
                float4 pv = *(const float4*)(pj + k);
                d = fmaf(mv.x, pv.x, fmaf(mv.y, pv.y, fmaf(mv.z, pv.z, fmaf(mv.w, pv.w, d))));
            }
            #pragma unroll
            for (int off = 1; off < 8; off <<= 1) d += __shfl_xor(d, off, 64);
            if (sub == 0) {
                sv[g] = fmaf(-2.f, d, mm[cand]);
                si[g] = cand;
            }
            __syncthreads();
            if (t == 0) {
                float bv = sv[0]; int bi = si[0];
                for (int gg = 1; gg < 32; ++gg) {
                    float v = sv[gg]; int ii = si[gg];
                    if (v < bv || (v == bv && ii < bi)) { bv = v; bi = ii; }
                }
                bidx[row] = bi;
                sbest = bi;
            }
            __syncthreads();
            int best = sbest;
            if (t < 128)
                *(float4*)(out0 + (size_t)row * DIMH + t * 4) =
                    *(const float4*)(Mem + (size_t)best * DIMH + t * 4);
        }
    }
}

// ---------- upd = ((Ph+Pl) - mem[bidx]) @ Wu^T + b; out1[bidx] += 0.5*upd ----------
__global__ __launch_bounds__(256, 2) void k_upd_mfma(
        const unsigned short* __restrict__ Ph, const unsigned short* __restrict__ Pl,
        const float* __restrict__ Mem, const int* __restrict__ bidx,
        const unsigned short* __restrict__ Bh, const unsigned short* __restrict__ Bl,
        const float* __restrict__ bias, float* __restrict__ out1) {
    __shared__ unsigned short sAh[128 * 32];
    __shared__ unsigned short sAl[128 * 32];
    __shared__ unsigned short sBh[128 * 32];
    __shared__ unsigned short sBl[128 * 32];
    __shared__ int ridx[128];
    const int t = threadIdx.x, w = t >> 6, l = t & 63;
    const int wm = w >> 1, wn = w & 1, lane16 = l & 15, quad = l >> 4;
    const int bm = blockIdx.x * 128, bn = blockIdx.y * 128;
    const int r0 = t >> 2, k0 = (t & 3) * 8, r1 = (t + 256) >> 2;
    const int lds0 = t * 8, lds1 = t * 8 + 2048;
    const int ar = t >> 1, ak = (t & 1) * 16;
    if (t < 128) ridx[t] = bidx[bm + t];
    __syncthreads();

    f32x4 acc[4][4];
    #pragma unroll
    for (int mf = 0; mf < 4; ++mf)
        #pragma unroll
        for (int nf = 0; nf < 4; ++nf) acc[mf][nf] = (f32x4){0.f, 0.f, 0.f, 0.f};

    for (int kc = 0; kc < DIMH; kc += 32) {
        async_copy16(Bh + (size_t)(bn + r0) * DIMH + kc + k0, sBh + lds0);
        async_copy16(Bh + (size_t)(bn + r1) * DIMH + kc + k0, sBh + lds1);
        async_copy16(Bl + (size_t)(bn + r0) * DIMH + kc + k0, sBl + lds0);
        async_copy16(Bl + (size_t)(bn + r1) * DIMH + kc + k0, sBl + lds1);
        {
            const unsigned short* ph = Ph + (size_t)(bm + ar) * DIMH + kc + ak;
            const unsigned short* pl = Pl + (size_t)(bm + ar) * DIMH + kc + ak;
            union { unsigned short us[16]; int4 q[2]; } hq, lq;
            hq.q[0] = *(const int4*)ph; hq.q[1] = *(const int4*)(ph + 8);
            lq.q[0] = *(const int4*)pl; lq.q[1] = *(const int4*)(pl + 8);
            const float* mrow = Mem + (size_t)ridx[ar] * DIMH + kc + ak;
            float4 m0 = *(const float4*)(mrow), m1 = *(const float4*)(mrow + 4);
            float4 m2 = *(const float4*)(mrow + 8), m3 = *(const float4*)(mrow + 12);
            float mv[16] = {m0.x, m0.y, m0.z, m0.w, m1.x, m1.y, m1.z, m1.w,
                            m2.x, m2.y, m2.z, m2.w, m3.x, m3.y, m3.z, m3.w};
            union { unsigned short us[16]; int4 q[2]; } hv, lv;
            #pragma unroll
            for (int j = 0; j < 16; ++j) {
                float d = bf16_to_f(hq.us[j]) + bf16_to_f(lq.us[j]) - mv[j];
                unsigned short hh = bf16_rne(d);
                hv.us[j] = hh;
                lv.us[j] = bf16_rne(d - bf16_to_f(hh));
            }
            *(int4*)(sAh + ar * 32 + ak) = hv.q[0];
            *(int4*)(sAh + ar * 32 + ak + 8) = hv.q[1];
            *(int4*)(sAl + ar * 32 + ak) = lv.q[0];
            *(int4*)(sAl + ar * 32 + ak + 8) = lv.q[1];
        }
        __syncthreads();
        bf16x8 ah[4], al[4];
        #pragma unroll
        for (int mf = 0; mf < 4; ++mf) {
            int r = wm * 64 + mf * 16 + lane16;
            ah[mf] = *(const bf16x8*)(sAh + r * 32 + quad * 8);
            al[mf] = *(const bf16x8*)(sAl + r * 32 + quad * 8);
        }
        #pragma unroll
        for (int nf = 0; nf < 4; ++nf) {
            int r = wn * 64 + nf * 16 + lane16;
            bf16x8 bh = *(const bf16x8*)(sBh + r * 32 + quad * 8);
            bf16x8 bl = *(const bf16x8*)(sBl + r * 32 + quad * 8);
            #pragma unroll
            for (int mf = 0; mf < 4; ++mf) {
                acc[mf][nf] = __builtin_amdgcn_mfma_f32_16x16x32_bf16(ah[mf], bh, acc[mf][nf], 0, 0, 0);
                acc[mf][nf] = __builtin_amdgcn_mfma_f32_16x16x32_bf16(ah[mf], bl, acc[mf][nf], 0, 0, 0);
                acc[mf][nf] = __builtin_amdgcn_mfma_f32_16x16x32_bf16(al[mf], bh, acc[mf][nf], 0, 0, 0);
            }
        }
        __syncthreads();
    }
    #pragma unroll
    for (int nf = 0; nf < 4; ++nf) {
        int col = bn + wn * 64 + nf * 16 + lane16;
        float bb = bias[col];
        #pragma unroll
        for (int mf = 0; mf < 4; ++mf)
            #pragma unroll
            for (int rr = 0; rr < 4; ++rr) {
                int rowl = wm * 64 + mf * 16 + quad * 4 + rr;
                int tgt = ridx[rowl];
                atomicAdd(out1 + (size_t)tgt * DIMH + col, 0.5f * (acc[mf][nf][rr] + bb));
            }
    }
}

extern "C" void kernel_launch(void* const* d_in, const int* in_sizes, int n_in,
                              void* d_out, int out_size, void* d_ws, size_t ws_size,
                              hipStream_t stream) {
    const float* visual = (const float*)d_in[0];
    const float* memory = (const float*)d_in[1];
    const float* W_proj = (const float*)d_in[2];
    const float* b_proj = (const float*)d_in[3];
    const float* W_upd  = (const float*)d_in[4];
    const float* b_upd  = (const float*)d_in[5];
    float* out0 = (float*)d_out;
    float* out1 = out0 + (size_t)NROWS * DIMH;

    char* ws = (char*)d_ws;
    unsigned short* Ph  = (unsigned short*)ws;
    unsigned short* Pl  = Ph + (size_t)NROWS * DIMH;
    unsigned short* P16 = Pl + (size_t)NROWS * DIMH;
    unsigned short* M16 = P16 + (size_t)NROWS * DIMH;
    unsigned short* Wph = M16 + (size_t)MEMN * DIMH;
    unsigned short* Wpl = Wph + (size_t)DIMH * DIMIN;
    unsigned short* Wuh = Wpl + (size_t)DIMH * DIMIN;
    unsigned short* Wul = Wuh + (size_t)DIMH * DIMH;
    float* mm   = (float*)(Wul + (size_t)DIMH * DIMH);
    float* cval = mm + MEMN;
    float* cv2  = cval + (size_t)NROWS * CSLOTS;
    int*   cidx = (int*)(cv2 + (size_t)NROWS * CSLOTS);
    int*   cidx2 = cidx + (size_t)NROWS * CSLOTS;
    int*   bidx = cidx2 + (size_t)NROWS * CSLOTS;
    int*   list = bidx + NROWS;
    int*   count = list + NROWS;

    k_sumsq_split<<<MEMN / 4, 256, 0, stream>>>(memory, mm, M16);
    k_split<<<(DIMH * DIMIN) / (8 * 256), 256, 0, stream>>>(W_proj, Wph, Wpl, DIMH * DIMIN);
    k_split<<<(DIMH * DIMH) / (8 * 256), 256, 0, stream>>>(W_upd, Wuh, Wul, DIMH * DIMH);
    k_proj_mfma<<<dim3(NROWS / 128, DIMH / 128), 256, 0, stream>>>(
        visual, Wph, Wpl, b_proj, Ph, Pl, P16);
    k_argmin_mfma<<<(NROWS / 128) * NSPLIT, 512, 0, stream>>>(
        P16, M16, mm, cval, cidx, cv2, cidx2);
    hipMemsetAsync(count, 0, 4, stream);
    k_merge_gather<<<NROWS / 4, 256, 0, stream>>>(
        cval, cidx, cv2, memory, out0, bidx, count, list);
    k_rescan<<<1024, 256, 0, stream>>>(
        visual, W_proj, b_proj, memory, mm, count, list, cidx, cidx2, bidx, out0);
    hipMemcpyAsync(out1, memory, (size_t)MEMN * DIMH * 4, hipMemcpyDeviceToDevice, stream);
    k_upd_mfma<<<dim3(NROWS / 128, DIMH / 128), 256, 0, stream>>>(
        Ph, Pl, memory, bidx, Wuh, Wul, b_upd, out1);
}